// Round 4
// baseline (1355.858 us; speedup 1.0000x reference)
//
#include <hip/hip_runtime.h>
#include <stdint.h>

// ---------------------------------------------------------------------------
// VQ-VAE forward on MI355X (gfx950).  Round 4.
// KEY INSIGHT (r2/r3 bit-identical single-flip failure): the np reference's
// dists = s1 + s2 - 2*zG are fp32-quantized at ulp(s1~0.016)=1.9e-9; rows
// with exact top-2 gap < 1 ulp TIE in fp32 and np.argmin picks FIRST INDEX.
// A fine-grained distance (r2/r3's 0.5*||c||^2 - z.c) tracks exact ordering
// and can never reproduce that. Fix: replicate np's formula structure AND
// numpy's pairwise-summation order for s1/s2, on np's rounding grid.
// Encoder: fp16-split MFMA (enc0, enc1); h1 stored fp32; z-layer = fp32 VALU
// GEMM with pristine fp32 weights (z error vs np ~4e-9 -> s1 within ~0.5 ulp).
// Decoder: plain bf16 MFMA (error ~1.2e-7 < 3.46e-7 threshold).
// ---------------------------------------------------------------------------

typedef unsigned int u32;
typedef __attribute__((ext_vector_type(8))) short   short8;  // 8 x 16-bit
typedef __attribute__((ext_vector_type(8))) _Float16 half8;
typedef __attribute__((ext_vector_type(4))) float   floatx4; // MFMA C/D

__device__ __forceinline__ unsigned short f2bf(float f) {    // RNE fp32->bf16
    u32 u = __float_as_uint(f);
    u += 0x7fffu + ((u >> 16) & 1u);
    return (unsigned short)(u >> 16);
}
__device__ __forceinline__ float bf2f(unsigned short h) {
    return __uint_as_float(((u32)h) << 16);
}
__device__ __forceinline__ unsigned short f2h(float f) {     // RNE fp32->fp16
    _Float16 h = (_Float16)f;
    return __builtin_bit_cast(unsigned short, h);
}
__device__ __forceinline__ float h2f(unsigned short u) {
    return (float)__builtin_bit_cast(_Float16, u);
}

#define GLDS16(gp, lp) __builtin_amdgcn_global_load_lds(                      \
    (const __attribute__((address_space(1))) u32*)(const void*)(gp),          \
    (__attribute__((address_space(3))) u32*)(void*)(lp), 16, 0, 0)

// fp32 -> (hi, lo) fp16 split (encoder operands)
__global__ __launch_bounds__(256)
void cvt_split_h(const float* __restrict__ in, unsigned short* __restrict__ hi,
                 unsigned short* __restrict__ lo, int n)
{
    int i = (blockIdx.x * 256 + threadIdx.x) * 4;
    if (i >= n) return;
    const float4 v = *(const float4*)(in + i);
    unsigned short a = f2h(v.x), b = f2h(v.y), c = f2h(v.z), d = f2h(v.w);
    *(ushort4*)(hi + i) = make_ushort4(a, b, c, d);
    *(ushort4*)(lo + i) = make_ushort4(f2h(v.x - h2f(a)), f2h(v.y - h2f(b)),
                                       f2h(v.z - h2f(c)), f2h(v.w - h2f(d)));
}

// fp32 -> bf16 (decoder weights)
__global__ __launch_bounds__(256)
void cvt1(const float* __restrict__ in, unsigned short* __restrict__ hi, int n)
{
    int i = (blockIdx.x * 256 + threadIdx.x) * 4;
    if (i >= n) return;
    const float4 v = *(const float4*)(in + i);
    *(ushort4*)(hi + i) = make_ushort4(f2bf(v.x), f2bf(v.y), f2bf(v.z), f2bf(v.w));
}

// s2[c] = np.sum(codebook[c]**2) with numpy's EXACT pairwise-64 order:
// 8 accumulators over strided elements, then ((r0+r1)+(r2+r3))+((r4+r5)+(r6+r7))
__global__ __launch_bounds__(256)
void prep_s2(const float* __restrict__ cb, float* __restrict__ s2)
{
    int c = blockIdx.x * 256 + threadIdx.x;   // grid 4 -> 1024 codes
    const float* a = cb + (size_t)c * 64;
    float r[8];
#pragma unroll
    for (int j = 0; j < 8; ++j) r[j] = __fmul_rn(a[j], a[j]);
#pragma unroll
    for (int b = 1; b < 8; ++b)
#pragma unroll
        for (int j = 0; j < 8; ++j)
            r[j] = __fadd_rn(r[j], __fmul_rn(a[8 * b + j], a[8 * b + j]));
    float s = __fadd_rn(__fadd_rn(__fadd_rn(r[0], r[1]), __fadd_rn(r[2], r[3])),
                        __fadd_rn(__fadd_rn(r[4], r[5]), __fadd_rn(r[6], r[7])));
    s2[c] = s;
}

// transpose z_w [256,512] -> zwT [512,256] for coalesced VALU GEMM loads
__global__ __launch_bounds__(256)
void transpose_zw(const float* __restrict__ zw, float* __restrict__ zwT)
{
    int i = blockIdx.x * 256 + threadIdx.x;   // grid 512 -> 131072
    int k = i >> 8, c = i & 255;
    zwT[i] = zw[c * 512 + k];
}

// z = h1 @ z_w^T + z_b in fp32 VALU (pristine weights, 4-phase accumulators).
// 8 rows x 256 cols per block; h1 tile staged in LDS.
__global__ __launch_bounds__(256)
void zgemm(const float* __restrict__ h1, const float* __restrict__ zwT,
           const float* __restrict__ zb, float* __restrict__ zf)
{
    __shared__ float sh[8 * 512];
    const int t = threadIdx.x;
    const int r0 = blockIdx.x * 8;            // grid 1024 -> 8192 rows
    const float4* src = (const float4*)(h1 + (size_t)r0 * 512);
    float4* dst = (float4*)sh;
#pragma unroll
    for (int i = 0; i < 4; ++i) dst[t + i * 256] = src[t + i * 256];
    __syncthreads();

    const int col = t;                        // N = 256
    float acc[8][4];
#pragma unroll
    for (int r = 0; r < 8; ++r)
#pragma unroll
        for (int p = 0; p < 4; ++p) acc[r][p] = 0.f;

    for (int k = 0; k < 512; k += 4) {
        float w0 = zwT[(k + 0) * 256 + col];
        float w1 = zwT[(k + 1) * 256 + col];
        float w2 = zwT[(k + 2) * 256 + col];
        float w3 = zwT[(k + 3) * 256 + col];
#pragma unroll
        for (int r = 0; r < 8; ++r) {
            float4 hv = *(const float4*)(sh + r * 512 + k);
            acc[r][0] += hv.x * w0;
            acc[r][1] += hv.y * w1;
            acc[r][2] += hv.z * w2;
            acc[r][3] += hv.w * w3;
        }
    }
    const float bv = zb[col];
#pragma unroll
    for (int r = 0; r < 8; ++r) {
        float s = ((acc[r][0] + acc[r][1]) + (acc[r][2] + acc[r][3])) + bv;
        zf[(size_t)(r0 + r) * 256 + col] = s;
    }
}

// VQ with np's exact fp32 distance profile:
//   dist_j = fl( fl(s1 + s2_j) - 2*G_j ),  s1 = np-pairwise-64 of fl(z_i^2)
// argmin strict-< ascending (np first-index tie-break, incl. exact fp32 ties).
__global__ __launch_bounds__(256)
void vq_kernel(const float* __restrict__ z, const float* __restrict__ cb,
               const float* __restrict__ s2, unsigned short* __restrict__ zq)
{
    const int t   = threadIdx.x;
    const int sub = t & 3;
    const int row = blockIdx.x * 64 + (t >> 2);   // grid 512 -> 32768 rows
    const float* zrow = z + (size_t)row * 64;
    float ze[64];
#pragma unroll
    for (int d = 0; d < 16; ++d) {
        float4 v = *(const float4*)(zrow + d * 4);
        ze[d * 4 + 0] = v.x; ze[d * 4 + 1] = v.y;
        ze[d * 4 + 2] = v.z; ze[d * 4 + 3] = v.w;
    }
    // s1: numpy pairwise order, contraction-proof
    float r[8];
#pragma unroll
    for (int j = 0; j < 8; ++j) r[j] = __fmul_rn(ze[j], ze[j]);
#pragma unroll
    for (int b = 1; b < 8; ++b)
#pragma unroll
        for (int j = 0; j < 8; ++j)
            r[j] = __fadd_rn(r[j], __fmul_rn(ze[8 * b + j], ze[8 * b + j]));
    const float s1 = __fadd_rn(
        __fadd_rn(__fadd_rn(r[0], r[1]), __fadd_rn(r[2], r[3])),
        __fadd_rn(__fadd_rn(r[4], r[5]), __fadd_rn(r[6], r[7])));

    float bestd = 3.4e38f;
    int bestj = 0;
    for (int jj = 0; jj < 256; ++jj) {
        const int j = jj * 4 + sub;
        const float* crow = cb + (size_t)j * 64;
        float a0 = 0.f, a1 = 0.f, a2 = 0.f, a3 = 0.f;
#pragma unroll
        for (int d = 0; d < 16; ++d) {
            float4 cv = *(const float4*)(crow + d * 4);
            a0 += ze[d * 4 + 0] * cv.x;
            a1 += ze[d * 4 + 1] * cv.y;
            a2 += ze[d * 4 + 2] * cv.z;
            a3 += ze[d * 4 + 3] * cv.w;
        }
        const float g  = (a0 + a1) + (a2 + a3);
        const float t1 = __fadd_rn(s1, s2[j]);       // np: (s1 + s2) first
        const float dist = __fadd_rn(t1, -(2.0f * g)); // then - 2*G (2*g exact)
        if (dist < bestd) { bestd = dist; bestj = j; } // strict <: first idx
    }
#pragma unroll
    for (int m = 1; m <= 2; m <<= 1) {
        float od = __shfl_xor(bestd, m, 64);
        int   oj = __shfl_xor(bestj, m, 64);
        if (od < bestd || (od == bestd && oj < bestj)) { bestd = od; bestj = oj; }
    }
    const float* cbest = cb + (size_t)bestj * 64;
#pragma unroll
    for (int q = 0; q < 4; ++q) {
        int dq = sub * 4 + q;
        float4 cv = *(const float4*)(cbest + dq * 4);
        float o0 = ze[dq * 4 + 0] + (cv.x - ze[dq * 4 + 0]);
        float o1 = ze[dq * 4 + 1] + (cv.y - ze[dq * 4 + 1]);
        float o2 = ze[dq * 4 + 2] + (cv.z - ze[dq * 4 + 2]);
        float o3 = ze[dq * 4 + 3] + (cv.w - ze[dq * 4 + 3]);
        *(ushort4*)(zq + (size_t)row * 64 + dq * 4) =
            make_ushort4(f2bf(o0), f2bf(o1), f2bf(o2), f2bf(o3));
    }
}

// ---------------------------------------------------------------------------
// GEMM: C[M,N] = A[M,K] * B[N,K]^T + bias.  128x128 tile, 4 waves (64x64),
// BK=32, global_load_lds width=16, 16x16x32 MFMA.
// DT: 1 = fp16 operands, 0 = bf16.  TERMS: 3 = split, 1 = plain.
// OUT: 0 = fp32 Cf, 1 = bf16 Ch, 2 = fp16 split (Ch, Cl).
template<int DT>
__device__ __forceinline__ floatx4 mfma16(short8 a, short8 b, floatx4 c) {
    if (DT)
        return __builtin_amdgcn_mfma_f32_16x16x32_f16(
            __builtin_bit_cast(half8, a), __builtin_bit_cast(half8, b), c, 0, 0, 0);
    return __builtin_amdgcn_mfma_f32_16x16x32_bf16(a, b, c, 0, 0, 0);
}

template<int DT, int TERMS, int RELU, int OUT>
__global__ __launch_bounds__(256)
void gemm_k(const unsigned short* __restrict__ Ah, const unsigned short* __restrict__ Al,
            const unsigned short* __restrict__ Bh, const unsigned short* __restrict__ Bl,
            const float* __restrict__ bias,
            float* __restrict__ Cf,
            unsigned short* __restrict__ Ch, unsigned short* __restrict__ Cl,
            int M, int N, int K)
{
    __shared__ unsigned short sAh[4096], sBh[4096];
    __shared__ unsigned short sAl[TERMS >= 3 ? 4096 : 64];
    __shared__ unsigned short sBl[TERMS >= 3 ? 4096 : 64];

    const int t    = threadIdx.x;
    const int wave = t >> 6;
    const int lane = t & 63;
    const int bm = blockIdx.y * 128;
    const int bn = blockIdx.x * 128;
    const int wm = (wave & 1) * 64;
    const int wn = (wave >> 1) * 64;

    floatx4 acc[4][4];
#pragma unroll
    for (int i = 0; i < 4; ++i)
#pragma unroll
        for (int j = 0; j < 4; ++j) acc[i][j] = (floatx4){0.f, 0.f, 0.f, 0.f};

    const int c0 = wave, c1 = wave + 4;
    const int skb = (lane & 3) * 8;
    const size_t aoff0 = (size_t)(bm + c0 * 16 + (lane >> 2)) * K + skb;
    const size_t aoff1 = (size_t)(bm + c1 * 16 + (lane >> 2)) * K + skb;
    const size_t boff0 = (size_t)(bn + c0 * 16 + (lane >> 2)) * K + skb;
    const size_t boff1 = (size_t)(bn + c1 * 16 + (lane >> 2)) * K + skb;

    const int fr = lane & 15;
    const int kq = lane >> 4;

    for (int k0 = 0; k0 < K; k0 += 32) {
        __syncthreads();
        GLDS16(Ah + aoff0 + k0, sAh + c0 * 512);
        GLDS16(Ah + aoff1 + k0, sAh + c1 * 512);
        GLDS16(Bh + boff0 + k0, sBh + c0 * 512);
        GLDS16(Bh + boff1 + k0, sBh + c1 * 512);
        if (TERMS >= 3) {
            GLDS16(Al + aoff0 + k0, sAl + c0 * 512);
            GLDS16(Al + aoff1 + k0, sAl + c1 * 512);
            GLDS16(Bl + boff0 + k0, sBl + c0 * 512);
            GLDS16(Bl + boff1 + k0, sBl + c1 * 512);
        }
        __syncthreads();

        short8 ah[4], bh[4], al[4], bl[4];
#pragma unroll
        for (int i = 0; i < 4; ++i) {
            const int ao = (wm + i * 16 + fr) * 32 + kq * 8;
            const int bo = (wn + i * 16 + fr) * 32 + kq * 8;
            ah[i] = *(const short8*)(sAh + ao);
            bh[i] = *(const short8*)(sBh + bo);
            if (TERMS >= 3) {
                al[i] = *(const short8*)(sAl + ao);
                bl[i] = *(const short8*)(sBl + bo);
            }
        }
#pragma unroll
        for (int i = 0; i < 4; ++i)
#pragma unroll
            for (int j = 0; j < 4; ++j) {
                if (TERMS >= 3) {
                    acc[i][j] = mfma16<DT>(al[i], bh[j], acc[i][j]);
                    acc[i][j] = mfma16<DT>(ah[i], bl[j], acc[i][j]);
                }
                acc[i][j] = mfma16<DT>(ah[i], bh[j], acc[i][j]);
            }
    }

    // C/D layout: col = lane&15, row = (lane>>4)*4 + reg
#pragma unroll
    for (int j = 0; j < 4; ++j) {
        const int col = bn + wn + j * 16 + fr;
        const float bv = bias[col];
#pragma unroll
        for (int i = 0; i < 4; ++i) {
#pragma unroll
            for (int rr = 0; rr < 4; ++rr) {
                const int row = bm + wm + i * 16 + kq * 4 + rr;
                float v = acc[i][j][rr] + bv;
                if (RELU) v = fmaxf(v, 0.f);
                const size_t idx = (size_t)row * N + col;
                if (OUT == 0) {
                    Cf[idx] = v;
                } else if (OUT == 1) {
                    Ch[idx] = f2bf(v);
                } else {
                    unsigned short h = f2h(v);
                    Ch[idx] = h;
                    Cl[idx] = f2h(v - h2f(h));
                }
            }
        }
    }
}

// ---------------------------------------------------------------------------
extern "C" void kernel_launch(void* const* d_in, const int* in_sizes, int n_in,
                              void* d_out, int out_size, void* d_ws, size_t ws_size,
                              hipStream_t stream)
{
    const float* x        = (const float*)d_in[0];
    const float* enc0_w   = (const float*)d_in[1];
    const float* enc0_b   = (const float*)d_in[2];
    const float* enc1_w   = (const float*)d_in[3];
    const float* enc1_b   = (const float*)d_in[4];
    const float* z_w      = (const float*)d_in[5];
    const float* z_b      = (const float*)d_in[6];
    const float* codebook = (const float*)d_in[7];
    const float* dec0_w   = (const float*)d_in[8];
    const float* dec0_b   = (const float*)d_in[9];
    const float* dec1_w   = (const float*)d_in[10];
    const float* dec1_b   = (const float*)d_in[11];
    const float* out_w    = (const float*)d_in[12];
    const float* out_b    = (const float*)d_in[13];
    float* xrec = (float*)d_out;

    const size_t MB = 1048576;
    char* ws = (char*)d_ws;
    char* ob = (char*)d_out;

    // x split lives in d_out (dead after enc0; rewritten by out-GEMM)
    unsigned short* xh   = (unsigned short*)(ob);             // [0,32M) of d_out
    unsigned short* xl   = (unsigned short*)(ob + 32 * MB);   // [32M,64M)
    // ws map (peak 50 MB), lifetimes audited disjoint:
    unsigned short* h0h  = (unsigned short*)(ws);             // [0,16M)  enc0->enc1
    unsigned short* h0l  = (unsigned short*)(ws + 16 * MB);   // [16M,32M)
    unsigned short* w0h  = (unsigned short*)(ws + 32 * MB);   // [32M,36M) ->enc0
    unsigned short* w0l  = (unsigned short*)(ws + 36 * MB);   // [36M,40M)
    unsigned short* w1h  = (unsigned short*)(ws + 48 * MB);   // [48M,49M) ->enc1
    unsigned short* w1l  = (unsigned short*)(ws + 49 * MB);   // [49M,50M)
    float*          h1f  = (float*)(ws + 32 * MB);            // [32M,48M) enc1->zgemm (over dead w0)
    // small tensors over dead h0 region (cvt'd after enc1):
    float*          s2   = (float*)(ws);                      // [0,4K)
    float*          zwT  = (float*)(ws + 524288);             // [512K,1M)
    unsigned short* wd0h = (unsigned short*)(ws + 1 * MB);    // [1M,1.25M)
    unsigned short* wd1h = (unsigned short*)(ws + 1572864);   // [1.5M,2.5M)
    unsigned short* woh  = (unsigned short*)(ws + 2621440);   // [2.5M,6.5M)
    float*          zf   = (float*)(ws + 8 * MB);             // [8M,16M)  z->vq
    unsigned short* zq   = (unsigned short*)(ws + 16 * MB);   // [16M,20M) vq->dec0
    unsigned short* d0   = (unsigned short*)(ws + 20 * MB);   // [20M,28M) dec0->dec1
    unsigned short* d1   = (unsigned short*)(ws + 32 * MB);   // [32M,48M) dec1->out (over dead h1f)

    dim3 blk(256);

    cvt_split_h<<<16384, blk, 0, stream>>>(x, xh, xl, 16777216);
    cvt_split_h<<<2048,  blk, 0, stream>>>(enc0_w, w0h, w0l, 2097152);
    cvt_split_h<<<512,   blk, 0, stream>>>(enc1_w, w1h, w1l, 524288);
    // enc0: relu(x @ W0^T + b0) -> fp16-split h0
    gemm_k<1, 3, 1, 2><<<dim3(8, 64), blk, 0, stream>>>(xh, xl, w0h, w0l, enc0_b,
                                                        nullptr, h0h, h0l, 8192, 1024, 2048);
    // enc1: relu(h0 @ W1^T + b1) -> fp32 h1 (no storage quantization)
    gemm_k<1, 3, 1, 0><<<dim3(4, 64), blk, 0, stream>>>(h0h, h0l, w1h, w1l, enc1_b,
                                                        h1f, nullptr, nullptr, 8192, 512, 1024);
    // h0 region dead -> small preps into [0,6.5M)
    prep_s2<<<4, blk, 0, stream>>>(codebook, s2);
    transpose_zw<<<512, blk, 0, stream>>>(z_w, zwT);
    cvt1<<<128, blk, 0, stream>>>(dec0_w, wd0h, 131072);
    cvt1<<<512, blk, 0, stream>>>(dec1_w, wd1h, 524288);
    cvt1<<<2048, blk, 0, stream>>>(out_w, woh, 2097152);
    // z = h1 @ Wz^T + bz, fp32 VALU with pristine weights
    zgemm<<<1024, blk, 0, stream>>>(h1f, zwT, z_b, zf);
    // VQ argmin with np's exact fp32 distance profile + first-index ties
    vq_kernel<<<512, blk, 0, stream>>>(zf, codebook, s2, zq);
    // decoder (plain bf16)
    gemm_k<0, 1, 1, 1><<<dim3(4, 64), blk, 0, stream>>>(zq, nullptr, wd0h, nullptr, dec0_b,
                                                        nullptr, d0, nullptr, 8192, 512, 256);
    gemm_k<0, 1, 1, 1><<<dim3(8, 64), blk, 0, stream>>>(d0, nullptr, wd1h, nullptr, dec1_b,
                                                        nullptr, d1, nullptr, 8192, 1024, 512);
    gemm_k<0, 1, 0, 0><<<dim3(16, 64), blk, 0, stream>>>(d1, nullptr, woh, nullptr, out_b,
                                                         xrec, nullptr, nullptr, 8192, 2048, 1024);
}